// Round 2
// baseline (1910.384 us; speedup 1.0000x reference)
//
#include <hip/hip_runtime.h>
#include <math.h>

#define B_ 8
#define C_ 64
#define H_ 50
#define W_ 65
#define N_ 3250
#define SIDE_ 57.0f
#define EPS_ 1e-5f

// ---------------- K0: zero the BN accumulators (ws is poisoned 0xAA each call) --------
__global__ void k_zero(float* __restrict__ acc) {
    acc[threadIdx.x] = 0.0f;   // 256 floats: sum[64], sumsq[64], scale[64], shift[64]
}

// ---------------- K1: fused 3x3 conv + bias + RoPE -> (B,N,C) layouts ----------------
// grid (H, B, 3convs), block 320 (260 active compute lanes: w=t%65, co-group=t/65)
__global__ __launch_bounds__(320) void k_conv_rope(
    const float* __restrict__ x,
    const float* __restrict__ wq, const float* __restrict__ bq,
    const float* __restrict__ wk, const float* __restrict__ bk,
    const float* __restrict__ wv, const float* __restrict__ bv,
    const float* __restrict__ fr,
    float* __restrict__ qr, float* __restrict__ kr, float* __restrict__ vv)
{
    const int h  = blockIdx.x;
    const int b  = blockIdx.y;
    const int cv = blockIdx.z;
    const float* wp = (cv == 0) ? wq : ((cv == 1) ? wk : wv);
    const float* bp = (cv == 0) ? bq : ((cv == 1) ? bk : bv);
    float*       op = (cv == 0) ? qr : ((cv == 1) ? kr : vv);

    __shared__ float xs[16 * 3 * 68];   // [ci16][row3][col68] cols store ww=-1..65 at +1
    __shared__ float ws[144 * 64];      // [r=ci*9+k][co ^ ((r&7)<<2)]; reused as transpose buf

    const int t   = threadIdx.x;
    const bool act = (t < 260);
    const int w   = t % 65;
    const int cog = t / 65;       // 0..3
    const int co0 = cog * 16;

    float acc[16];
#pragma unroll
    for (int i = 0; i < 16; ++i) acc[i] = 0.f;

    for (int ci0 = 0; ci0 < 64; ci0 += 16) {
        __syncthreads();
        // stage x tile: 16 ci x 3 rows x 67 cols
        {
            const int lane = t & 63;
            const int grp  = t >> 6;                   // 0..4
            for (int s = grp; s < 48; s += 5) {
                const int ci = s / 3, row = s % 3;
                const int hh = h + row - 1;
                int ww = lane - 1;
                float v = 0.f;
                if (hh >= 0 && hh < H_ && ww >= 0 && ww < W_)
                    v = x[((b * C_ + ci0 + ci) * H_ + hh) * W_ + ww];
                xs[(ci * 3 + row) * 68 + lane] = v;
                if (lane < 3) {
                    ww = 63 + lane;
                    v = 0.f;
                    if (hh >= 0 && hh < H_ && ww < W_)
                        v = x[((b * C_ + ci0 + ci) * H_ + hh) * W_ + ww];
                    xs[(ci * 3 + row) * 68 + 64 + lane] = v;
                }
            }
        }
        // stage weights for this ci chunk (coalesced read, swizzled LDS write)
        for (int l = t; l < 9216; l += 320) {
            const int co = l / 144;
            const int r  = l % 144;
            ws[r * 64 + (co ^ ((r & 7) << 2))] = wp[co * 576 + ci0 * 9 + r];
        }
        __syncthreads();
        if (act) {
#pragma unroll 1
            for (int ci = 0; ci < 16; ++ci) {
#pragma unroll
                for (int kh = 0; kh < 3; ++kh) {
#pragma unroll
                    for (int kw = 0; kw < 3; ++kw) {
                        const int r   = ci * 9 + kh * 3 + kw;
                        const float xv = xs[(ci * 3 + kh) * 68 + w + kw];
                        const int swz = (r & 7) << 2;
#pragma unroll
                        for (int u = 0; u < 4; ++u) {
                            const float4 wf = *(const float4*)&ws[r * 64 + ((co0 + u * 4) ^ swz)];
                            acc[u * 4 + 0] += xv * wf.x;
                            acc[u * 4 + 1] += xv * wf.y;
                            acc[u * 4 + 2] += xv * wf.z;
                            acc[u * 4 + 3] += xv * wf.w;
                        }
                    }
                }
            }
        }
    }

    if (act) {
#pragma unroll
        for (int i = 0; i < 16; ++i) acc[i] += bp[co0 + i];
        const int m = h * W_ + w;
        if (cv < 2 && m > 0) {       // RoPE on q,k for positions 1..N-1
            const float fi = (float)(m - 1);
            const float ty = floorf(fi / SIDE_);
            const float tx = fi - ty * SIDE_;
#pragma unroll
            for (int pl = 0; pl < 8; ++pl) {
                const int p = (co0 >> 1) + pl;
                const float ang = tx * fr[p] + ty * fr[32 + p];
                float sn, cs;
                sincosf(ang, &sn, &cs);
                const float a  = acc[2 * pl];
                const float bb = acc[2 * pl + 1];
                acc[2 * pl]     = a * cs - bb * sn;
                acc[2 * pl + 1] = a * sn + bb * cs;
            }
        }
    }
    __syncthreads();                 // ws now reused as [65][68] transpose buffer
    float* lds_t = ws;
    if (act) {
#pragma unroll
        for (int i = 0; i < 16; ++i) lds_t[w * 68 + co0 + i] = acc[i];
    }
    __syncthreads();
    {
        const int c   = t & 63;
        const int grp = t >> 6;
        for (int row = grp; row < 65; row += 5)
            op[((size_t)b * N_ + h * W_ + row) * C_ + c] = lds_t[row * 68 + c];
    }
}

// ---------------- K2: flash attention (fp32, online softmax) -------------------------
// grid (ceil(N/32), B), block 256. thread: mi=t>>3 (query row), g=t&7 (key-group).
// ks/vs stored with chunk-XOR swizzle: dword n*64 + ((c>>2 ^ n>>3)<<2) + (c&3)
__global__ __launch_bounds__(256) void k_flash(
    const float* __restrict__ qr, const float* __restrict__ kr, const float* __restrict__ vv,
    float* __restrict__ oo)
{
    const int b  = blockIdx.y;
    const int m0 = blockIdx.x * 32;
    const int t  = threadIdx.x;
    const int g  = t & 7;
    const int mi = t >> 3;

    __shared__ float qs[32 * 68];
    __shared__ float ks[64 * 64];
    __shared__ float vs[64 * 64];
    __shared__ float linv[32];

    {   // stage Q (zeros for out-of-range rows)
        const int c = t & 63, r4 = t >> 6;
#pragma unroll
        for (int i = 0; i < 8; ++i) {
            const int row = r4 + i * 4;
            const int m   = m0 + row;
            qs[row * 68 + c] = (m < N_) ? qr[((size_t)b * N_ + m) * 64 + c] : 0.f;
        }
    }

    float o[64];
#pragma unroll
    for (int i = 0; i < 64; ++i) o[i] = 0.f;
    float run_m = -1e30f, run_l = 0.f;

    const int ntiles = (N_ + 63) / 64;   // 51
    for (int tile = 0; tile < ntiles; ++tile) {
        __syncthreads();
        {   // stage K,V tile (swizzled, zero-padded)
            const int c = t & 63, r4 = t >> 6;
#pragma unroll
            for (int i = 0; i < 16; ++i) {
                const int row = r4 + i * 4;
                const int n   = tile * 64 + row;
                const int a   = row * 64 + ((((c >> 2) ^ (row >> 3)) << 2) | (c & 3));
                if (n < N_) {
                    ks[a] = kr[((size_t)b * N_ + n) * 64 + c];
                    vs[a] = vv[((size_t)b * N_ + n) * 64 + c];
                } else { ks[a] = 0.f; vs[a] = 0.f; }
            }
        }
        __syncthreads();

        // S row mi, cols g*8..g*8+7
        float p_[8];
#pragma unroll
        for (int j = 0; j < 8; ++j) p_[j] = 0.f;
#pragma unroll 4
        for (int c4 = 0; c4 < 16; ++c4) {
            const float4 q4 = *(const float4*)&qs[mi * 68 + (c4 << 2)];
#pragma unroll
            for (int j = 0; j < 8; ++j) {
                const float4 k4 = *(const float4*)&ks[((g << 3) + j) * 64 + ((c4 ^ g) << 2)];
                p_[j] += q4.x * k4.x + q4.y * k4.y + q4.z * k4.z + q4.w * k4.w;
            }
        }
        if (tile == ntiles - 1) {
#pragma unroll
            for (int j = 0; j < 8; ++j)
                if (tile * 64 + (g << 3) + j >= N_) p_[j] = -1e30f;
        }

        // online softmax (row state identical across the 8 g-lanes of a row)
        float tmax = p_[0];
#pragma unroll
        for (int j = 1; j < 8; ++j) tmax = fmaxf(tmax, p_[j]);
        tmax = fmaxf(tmax, __shfl_xor(tmax, 1));
        tmax = fmaxf(tmax, __shfl_xor(tmax, 2));
        tmax = fmaxf(tmax, __shfl_xor(tmax, 4));
        const float mnew = fmaxf(run_m, tmax);
        float tsum = 0.f;
#pragma unroll
        for (int j = 0; j < 8; ++j) { p_[j] = __expf(p_[j] - mnew); tsum += p_[j]; }
        tsum += __shfl_xor(tsum, 1);
        tsum += __shfl_xor(tsum, 2);
        tsum += __shfl_xor(tsum, 4);
        if (mnew > run_m) {          // skip O-rescale when max unchanged
            const float corr = __expf(run_m - mnew);
            run_l *= corr;
#pragma unroll
            for (int i = 0; i < 64; ++i) o[i] *= corr;
            run_m = mnew;
        }
        run_l += tsum;

        // PV: o[c] += sum_j p_[j] * V[n_j][c]
#pragma unroll 2
        for (int j = 0; j < 8; ++j) {
            const float pj = p_[j];
#pragma unroll
            for (int c4 = 0; c4 < 16; ++c4) {
                const float4 v4 = *(const float4*)&vs[((g << 3) + j) * 64 + ((c4 ^ g) << 2)];
                o[(c4 << 2) + 0] += pj * v4.x;
                o[(c4 << 2) + 1] += pj * v4.y;
                o[(c4 << 2) + 2] += pj * v4.z;
                o[(c4 << 2) + 3] += pj * v4.w;
            }
        }
    }

    // combine the 8 key-group partials per row (butterfly over low 3 lane bits)
#pragma unroll
    for (int i = 0; i < 64; ++i) {
        float v = o[i];
        v += __shfl_xor(v, 1);
        v += __shfl_xor(v, 2);
        v += __shfl_xor(v, 4);
        o[i] = v;
    }
    __syncthreads();                  // ks dead -> reuse as row_buf[32][68]
    float* row_buf = ks;
    if (g == 0) {
#pragma unroll
        for (int i = 0; i < 64; ++i) row_buf[mi * 68 + i] = o[i];
        linv[mi] = 1.0f / run_l;
    }
    __syncthreads();
    {
        const int c = t & 63, r4 = t >> 6;
#pragma unroll
        for (int i = 0; i < 8; ++i) {
            const int row = r4 + i * 4;
            const int m   = m0 + row;
            if (m < N_) oo[((size_t)b * N_ + m) * 64 + c] = row_buf[row * 68 + c] * linv[row];
        }
    }
}

// ---------------- K3: y = gamma*x + O^T, per-channel sum/sumsq -----------------------
// grid (ceil(N/64), B), block 256
__global__ __launch_bounds__(256) void k_bnstats(
    const float* __restrict__ x, const float* __restrict__ oo,
    const float* __restrict__ gamma, float* __restrict__ yy, float* __restrict__ accum)
{
    const int b    = blockIdx.y;
    const int m0   = blockIdx.x * 64;
    const int t    = threadIdx.x;
    const int lane = t & 63;
    __shared__ float ot[64 * 65];
    const float gm = gamma[0];
    {
        const int r4 = t >> 6;
#pragma unroll
        for (int i = 0; i < 16; ++i) {
            const int row = r4 + i * 4;
            const int m   = m0 + row;
            ot[row * 65 + lane] = (m < N_) ? oo[((size_t)b * N_ + m) * 64 + lane] : 0.f;
        }
    }
    __syncthreads();
    const int  m     = m0 + lane;
    const bool valid = (m < N_);
#pragma unroll
    for (int i = 0; i < 16; ++i) {
        const int c = (t >> 6) + (i << 2);
        float y = 0.f;
        if (valid) {
            const float xv = x[(size_t)(b * 64 + c) * N_ + m];
            y = gm * xv + ot[lane * 65 + c];
            yy[(size_t)(b * 64 + c) * N_ + m] = y;
        }
        float s1 = y, s2 = y * y;
#pragma unroll
        for (int d = 1; d < 64; d <<= 1) { s1 += __shfl_xor(s1, d); s2 += __shfl_xor(s2, d); }
        if (lane == 0) {
            atomicAdd(&accum[c], s1);
            atomicAdd(&accum[64 + c], s2);
        }
    }
}

// ---------------- K4: finalize per-channel scale/shift -------------------------------
__global__ void k_bnfin(const float* __restrict__ accum, const float* __restrict__ bnw,
                        const float* __restrict__ bnb, float* __restrict__ ss)
{
    const int c = threadIdx.x;              // 64
    const float cnt  = (float)(B_ * N_);    // 26000
    const float mean = accum[c] / cnt;
    const float var  = accum[64 + c] / cnt - mean * mean;
    const float sc   = bnw[c] * rsqrtf(var + EPS_);
    ss[c]      = sc;
    ss[64 + c] = bnb[c] - mean * sc;
}

// ---------------- K5: apply BN -------------------------------------------------------
__global__ __launch_bounds__(256) void k_bnapply(
    const float* __restrict__ yy, const float* __restrict__ ss, float* __restrict__ out)
{
    const int total = B_ * C_ * N_;
    for (int e = blockIdx.x * 256 + threadIdx.x; e < total; e += gridDim.x * 256) {
        const int c = (e / N_) & 63;
        out[e] = yy[e] * ss[c] + ss[64 + c];
    }
}

// ---------------- launch -------------------------------------------------------------
extern "C" void kernel_launch(void* const* d_in, const int* in_sizes, int n_in,
                              void* d_out, int out_size, void* d_ws, size_t ws_size,
                              hipStream_t stream) {
    const float* x     = (const float*)d_in[0];
    const float* wq    = (const float*)d_in[1];
    const float* bq    = (const float*)d_in[2];
    const float* wk    = (const float*)d_in[3];
    const float* bk    = (const float*)d_in[4];
    const float* wv    = (const float*)d_in[5];
    const float* bv    = (const float*)d_in[6];
    const float* fr    = (const float*)d_in[7];
    const float* gamma = (const float*)d_in[8];
    const float* bnw   = (const float*)d_in[9];
    const float* bnb   = (const float*)d_in[10];

    float* wsf = (float*)d_ws;                 // needs ~26.6 MB of workspace
    float* qr    = wsf;                        // (B,N,C)
    float* kr    = wsf + 1664000;
    float* vv    = wsf + 3328000;
    float* oo    = wsf + 4992000;              // attention out (B,N,C)
    float* yy    = qr;                         // (B,C,N), reuses qr after flash
    float* accum = wsf + 6656000;              // sum[64], sumsq[64]
    float* ss    = wsf + 6656128;              // scale[64], shift[64]
    float* outp  = (float*)d_out;

    k_zero<<<1, 256, 0, stream>>>(accum);
    k_conv_rope<<<dim3(H_, B_, 3), 320, 0, stream>>>(x, wq, bq, wk, bk, wv, bv, fr, qr, kr, vv);
    k_flash<<<dim3((N_ + 31) / 32, B_), 256, 0, stream>>>(qr, kr, vv, oo);
    k_bnstats<<<dim3((N_ + 63) / 64, B_), 256, 0, stream>>>(x, oo, gamma, yy, accum);
    k_bnfin<<<1, 64, 0, stream>>>(accum, bnw, bnb, ss);
    k_bnapply<<<1024, 256, 0, stream>>>(yy, ss, outp);
}

// Round 5
// 939.668 us; speedup vs baseline: 2.0330x; 2.0330x over previous
//
#include <hip/hip_runtime.h>
#include <math.h>

#define B_ 8
#define C_ 64
#define H_ 50
#define W_ 65
#define N_ 3250
#define NP_ 3264            // padded positions (51*64), 16B-aligned bf16 rows
#define SIDE_ 57.0f
#define EPS_ 1e-5f

typedef __attribute__((ext_vector_type(4))) float f32x4;
typedef __attribute__((ext_vector_type(8))) short s16x8;

__device__ __forceinline__ unsigned short rne_bf16(float f) {
    unsigned u = __builtin_bit_cast(unsigned, f);
    u += 0x7FFFu + ((u >> 16) & 1u);
    return (unsigned short)(u >> 16);
}
__device__ __forceinline__ float bf16_f(unsigned short h) {
    return __builtin_bit_cast(float, (unsigned)h << 16);
}

// builtin MFMA (guide-verified type pairing): compiler owns hazards + scheduling
#define MFMA16(acc, a, b) \
    (acc) = __builtin_amdgcn_mfma_f32_16x16x32_bf16((a), (b), (acc), 0, 0, 0)

// ---------------- K0: zero the BN accumulators --------------------------------------
__global__ void k_zero(float* __restrict__ acc) {
    acc[threadIdx.x] = 0.0f;
}

// ---------------- K1: fused 3x3 conv + bias + RoPE ----------------------------------
// outputs: qr fp32 (B,N,C); khg/klg bf16 split (B,NP,C); vgT bf16 (B,C,NP)
__global__ __launch_bounds__(320) void k_conv_rope(
    const float* __restrict__ x,
    const float* __restrict__ wq, const float* __restrict__ bq,
    const float* __restrict__ wk, const float* __restrict__ bk,
    const float* __restrict__ wv, const float* __restrict__ bv,
    const float* __restrict__ fr,
    float* __restrict__ qr, unsigned short* __restrict__ khg,
    unsigned short* __restrict__ klg, unsigned short* __restrict__ vgT)
{
    const int h  = blockIdx.x;
    const int b  = blockIdx.y;
    const int cv = blockIdx.z;
    const float* wp = (cv == 0) ? wq : ((cv == 1) ? wk : wv);
    const float* bp = (cv == 0) ? bq : ((cv == 1) ? bk : bv);

    __shared__ float xs[16 * 3 * 68];
    __shared__ float ws[144 * 64];

    const int t   = threadIdx.x;
    const bool act = (t < 260);
    const int w   = t % 65;
    const int cog = t / 65;
    const int co0 = cog * 16;

    float acc[16];
#pragma unroll
    for (int i = 0; i < 16; ++i) acc[i] = 0.f;

    for (int ci0 = 0; ci0 < 64; ci0 += 16) {
        __syncthreads();
        {
            const int lane = t & 63;
            const int grp  = t >> 6;
            for (int s = grp; s < 48; s += 5) {
                const int ci = s / 3, row = s % 3;
                const int hh = h + row - 1;
                int ww = lane - 1;
                float v = 0.f;
                if (hh >= 0 && hh < H_ && ww >= 0 && ww < W_)
                    v = x[((b * C_ + ci0 + ci) * H_ + hh) * W_ + ww];
                xs[(ci * 3 + row) * 68 + lane] = v;
                if (lane < 3) {
                    ww = 63 + lane;
                    v = 0.f;
                    if (hh >= 0 && hh < H_ && ww < W_)
                        v = x[((b * C_ + ci0 + ci) * H_ + hh) * W_ + ww];
                    xs[(ci * 3 + row) * 68 + 64 + lane] = v;
                }
            }
        }
        for (int l = t; l < 9216; l += 320) {
            const int co = l / 144;
            const int r  = l % 144;
            ws[r * 64 + (co ^ ((r & 7) << 2))] = wp[co * 576 + ci0 * 9 + r];
        }
        __syncthreads();
        if (act) {
#pragma unroll 1
            for (int ci = 0; ci < 16; ++ci) {
#pragma unroll
                for (int kh = 0; kh < 3; ++kh) {
#pragma unroll
                    for (int kw = 0; kw < 3; ++kw) {
                        const int r   = ci * 9 + kh * 3 + kw;
                        const float xv = xs[(ci * 3 + kh) * 68 + w + kw];
                        const int swz = (r & 7) << 2;
#pragma unroll
                        for (int u = 0; u < 4; ++u) {
                            const float4 wf = *(const float4*)&ws[r * 64 + ((co0 + u * 4) ^ swz)];
                            acc[u * 4 + 0] += xv * wf.x;
                            acc[u * 4 + 1] += xv * wf.y;
                            acc[u * 4 + 2] += xv * wf.z;
                            acc[u * 4 + 3] += xv * wf.w;
                        }
                    }
                }
            }
        }
    }

    if (act) {
#pragma unroll
        for (int i = 0; i < 16; ++i) acc[i] += bp[co0 + i];
    }

    if (cv == 2) {            // V: direct (B,C,NP) bf16 store, no RoPE, no transpose
        if (act) {
            const int n = h * W_ + w;
#pragma unroll
            for (int i = 0; i < 16; ++i)
                vgT[(size_t)(b * 64 + co0 + i) * NP_ + n] = rne_bf16(acc[i]);
        }
        return;               // uniform per block
    }

    if (act) {
        const int m = h * W_ + w;
        if (m > 0) {          // RoPE for q,k on positions 1..N-1
            const float fi = (float)(m - 1);
            const float ty = floorf(fi / SIDE_);
            const float tx = fi - ty * SIDE_;
#pragma unroll
            for (int pl = 0; pl < 8; ++pl) {
                const int p = (co0 >> 1) + pl;
                const float ang = tx * fr[p] + ty * fr[32 + p];
                float sn, cs;
                sincosf(ang, &sn, &cs);
                const float a  = acc[2 * pl];
                const float bb = acc[2 * pl + 1];
                acc[2 * pl]     = a * cs - bb * sn;
                acc[2 * pl + 1] = a * sn + bb * cs;
            }
        }
    }
    __syncthreads();                 // ws reused as [65][68] transpose buffer
    float* lds_t = ws;
    if (act) {
#pragma unroll
        for (int i = 0; i < 16; ++i) lds_t[w * 68 + co0 + i] = acc[i];
    }
    __syncthreads();
    {
        const int c   = t & 63;
        const int grp = t >> 6;
        for (int row = grp; row < 65; row += 5) {
            const float f = lds_t[row * 68 + c];
            const int pos = h * W_ + row;
            if (cv == 0) {
                qr[(size_t)(b * N_ + pos) * 64 + c] = f;
            } else {
                const size_t idx = (size_t)(b * NP_ + pos) * 64 + c;
                const unsigned short hh = rne_bf16(f);
                khg[idx] = hh;
                klg[idx] = rne_bf16(f - bf16_f(hh));
            }
        }
    }
}

// ---------------- K2: flash attention via split-bf16 MFMA ---------------------------
// 1 wave per block, 16 query rows per wave, KV tile = 64, no barriers.
// S = Qh*Kh + Ql*Kh + Qh*Kl (fp32-grade); PV = (Ph+Pl)*V (V single bf16).
__global__ __launch_bounds__(64) void k_flash2(
    const float* __restrict__ qr, const unsigned short* __restrict__ khg,
    const unsigned short* __restrict__ klg, const unsigned short* __restrict__ vgT,
    float* __restrict__ oo)
{
    const int b  = blockIdx.x;          // flat%8 == batch -> per-batch XCD pinning
    const int m0 = blockIdx.y << 4;
    const int l  = threadIdx.x;
    const int c  = l & 15;
    const int g  = l >> 4;

    __shared__ unsigned short pbh[1024];   // P-hi [16m][64n] bf16, byte^((m&7)<<4)
    __shared__ unsigned short pbl[1024];   // P-lo

    // Q A-frags: row = lane&15 (m0+c), k = ks*32 + g*8 + j
    s16x8 qh[2], ql[2];
#pragma unroll
    for (int ks = 0; ks < 2; ++ks) {
        const float* qp = qr + ((size_t)(b * N_ + m0 + c) * 64 + ks * 32 + g * 8);
        const f32x4 f0 = *(const f32x4*)qp;
        const f32x4 f1 = *(const f32x4*)(qp + 4);
#pragma unroll
        for (int j = 0; j < 4; ++j) {
            const unsigned short h0 = rne_bf16(f0[j]);
            qh[ks][j]     = (short)h0;
            ql[ks][j]     = (short)rne_bf16(f0[j] - bf16_f(h0));
            const unsigned short h1 = rne_bf16(f1[j]);
            qh[ks][4 + j] = (short)h1;
            ql[ks][4 + j] = (short)rne_bf16(f1[j] - bf16_f(h1));
        }
    }

    const f32x4 zero4 = {0.f, 0.f, 0.f, 0.f};
    f32x4 osum[4];
#pragma unroll
    for (int ct = 0; ct < 4; ++ct) osum[ct] = zero4;
    float run_m[4], run_l[4];
#pragma unroll
    for (int r = 0; r < 4; ++r) { run_m[r] = -1e30f; run_l[r] = 0.f; }

    for (int tile = 0; tile < 51; ++tile) {
        const int n0 = tile << 6;

        // ---- S = Q K^T (3-product split) ----
        f32x4 s4[4];
#pragma unroll
        for (int nt = 0; nt < 4; ++nt) s4[nt] = zero4;
#pragma unroll
        for (int ks = 0; ks < 2; ++ks) {
#pragma unroll
            for (int nt = 0; nt < 4; ++nt) {
                const size_t kb = (size_t)(b * NP_ + n0 + nt * 16 + c) * 64 + ks * 32 + g * 8;
                const s16x8 kh = *(const s16x8*)(khg + kb);
                const s16x8 kl = *(const s16x8*)(klg + kb);
                MFMA16(s4[nt], qh[ks], kh);
                MFMA16(s4[nt], ql[ks], kh);
                MFMA16(s4[nt], qh[ks], kl);
            }
        }

        if (tile == 50) {                  // mask padded columns
#pragma unroll
            for (int nt = 0; nt < 4; ++nt)
                if (n0 + nt * 16 + c >= N_) {
                    const f32x4 m4 = {-1e30f, -1e30f, -1e30f, -1e30f};
                    s4[nt] = m4;
                }
        }

        // ---- online softmax: row r lives in reg r across the 16 lanes of group g ----
        float corr[4];
#pragma unroll
        for (int r = 0; r < 4; ++r) {
            float tm = fmaxf(fmaxf(s4[0][r], s4[1][r]), fmaxf(s4[2][r], s4[3][r]));
            tm = fmaxf(tm, __shfl_xor(tm, 1));
            tm = fmaxf(tm, __shfl_xor(tm, 2));
            tm = fmaxf(tm, __shfl_xor(tm, 4));
            tm = fmaxf(tm, __shfl_xor(tm, 8));
            const float mnew = fmaxf(run_m[r], tm);
            corr[r] = __expf(run_m[r] - mnew);      // ==1 when max unchanged
            float ts = 0.f;
#pragma unroll
            for (int nt = 0; nt < 4; ++nt) {
                const float p = __expf(s4[nt][r] - mnew);
                s4[nt][r] = p;                      // reuse regs as fp32 P
                ts += p;
            }
            ts += __shfl_xor(ts, 1);
            ts += __shfl_xor(ts, 2);
            ts += __shfl_xor(ts, 4);
            ts += __shfl_xor(ts, 8);
            run_l[r] = run_l[r] * corr[r] + ts;
            run_m[r] = mnew;
        }
#pragma unroll
        for (int ct = 0; ct < 4; ++ct)
#pragma unroll
            for (int r = 0; r < 4; ++r) osum[ct][r] *= corr[r];

        // ---- P split -> LDS (swizzled [m][n]) ----
#pragma unroll
        for (int nt = 0; nt < 4; ++nt)
#pragma unroll
            for (int r = 0; r < 4; ++r) {
                const int m   = g * 4 + r;
                const int off = m * 128 + ((((nt * 16 + c) * 2)) ^ ((m & 7) << 4));
                const float p = s4[nt][r];
                const unsigned short ph = rne_bf16(p);
                *(unsigned short*)((char*)pbh + off) = ph;
                *(unsigned short*)((char*)pbl + off) = rne_bf16(p - bf16_f(ph));
            }

        // ---- O += P V ----
#pragma unroll
        for (int ks = 0; ks < 2; ++ks) {
            const int aoff = c * 128 + (((ks * 64 + g * 16)) ^ ((c & 7) << 4));
            const s16x8 pah = *(const s16x8*)((const char*)pbh + aoff);
            const s16x8 pal = *(const s16x8*)((const char*)pbl + aoff);
#pragma unroll
            for (int ct = 0; ct < 4; ++ct) {
                const size_t vb = (size_t)(b * 64 + ct * 16 + c) * NP_ + n0 + ks * 32 + g * 8;
                const s16x8 vf = *(const s16x8*)(vgT + vb);
                MFMA16(osum[ct], pah, vf);
                MFMA16(osum[ct], pal, vf);
            }
        }
    }

#pragma unroll
    for (int ct = 0; ct < 4; ++ct)
#pragma unroll
        for (int r = 0; r < 4; ++r) {
            const int m = m0 + g * 4 + r;          // C/D row = g*4+r, col = ct*16+c
            if (m < N_) oo[(size_t)(b * N_ + m) * 64 + ct * 16 + c] = osum[ct][r] / run_l[r];
        }
}

// ---------------- K3: y = gamma*x + O^T, per-channel sum/sumsq -----------------------
__global__ __launch_bounds__(256) void k_bnstats(
    const float* __restrict__ x, const float* __restrict__ oo,
    const float* __restrict__ gamma, float* __restrict__ yy, float* __restrict__ accum)
{
    const int b    = blockIdx.y;
    const int m0   = blockIdx.x * 64;
    const int t    = threadIdx.x;
    const int lane = t & 63;
    __shared__ float ot[64 * 65];
    const float gm = gamma[0];
    {
        const int r4 = t >> 6;
#pragma unroll
        for (int i = 0; i < 16; ++i) {
            const int row = r4 + i * 4;
            const int m   = m0 + row;
            ot[row * 65 + lane] = (m < N_) ? oo[((size_t)b * N_ + m) * 64 + lane] : 0.f;
        }
    }
    __syncthreads();
    const int  m     = m0 + lane;
    const bool valid = (m < N_);
#pragma unroll
    for (int i = 0; i < 16; ++i) {
        const int c = (t >> 6) + (i << 2);
        float y = 0.f;
        if (valid) {
            const float xv = x[(size_t)(b * 64 + c) * N_ + m];
            y = gm * xv + ot[lane * 65 + c];
            yy[(size_t)(b * 64 + c) * N_ + m] = y;
        }
        float s1 = y, s2 = y * y;
#pragma unroll
        for (int d = 1; d < 64; d <<= 1) { s1 += __shfl_xor(s1, d); s2 += __shfl_xor(s2, d); }
        if (lane == 0) {
            atomicAdd(&accum[c], s1);
            atomicAdd(&accum[64 + c], s2);
        }
    }
}

// ---------------- K4: finalize per-channel scale/shift -------------------------------
__global__ void k_bnfin(const float* __restrict__ accum, const float* __restrict__ bnw,
                        const float* __restrict__ bnb, float* __restrict__ ss)
{
    const int c = threadIdx.x;
    const float cnt  = (float)(B_ * N_);
    const float mean = accum[c] / cnt;
    const float var  = accum[64 + c] / cnt - mean * mean;
    const float sc   = bnw[c] * rsqrtf(var + EPS_);
    ss[c]      = sc;
    ss[64 + c] = bnb[c] - mean * sc;
}

// ---------------- K5: apply BN -------------------------------------------------------
__global__ __launch_bounds__(256) void k_bnapply(
    const float* __restrict__ yy, const float* __restrict__ ss, float* __restrict__ out)
{
    const int total = B_ * C_ * N_;
    for (int e = blockIdx.x * 256 + threadIdx.x; e < total; e += gridDim.x * 256) {
        const int c = (e / N_) & 63;
        out[e] = yy[e] * ss[c] + ss[64 + c];
    }
}

// ---------------- launch -------------------------------------------------------------
extern "C" void kernel_launch(void* const* d_in, const int* in_sizes, int n_in,
                              void* d_out, int out_size, void* d_ws, size_t ws_size,
                              hipStream_t stream) {
    const float* x     = (const float*)d_in[0];
    const float* wq    = (const float*)d_in[1];
    const float* bq    = (const float*)d_in[2];
    const float* wk    = (const float*)d_in[3];
    const float* bk    = (const float*)d_in[4];
    const float* wv    = (const float*)d_in[5];
    const float* bv    = (const float*)d_in[6];
    const float* fr    = (const float*)d_in[7];
    const float* gamma = (const float*)d_in[8];
    const float* bnw   = (const float*)d_in[9];
    const float* bnb   = (const float*)d_in[10];

    float* wsf = (float*)d_ws;                              // ~23.4 MB used
    float*          qr    = wsf;                            // (B,N,C)   fp32  1,664,000
    float*          oo    = wsf + 1664000;                  // (B,N,C)   fp32  1,664,000
    unsigned short* khg   = (unsigned short*)(wsf + 3328000); // (B,NP,C) bf16
    unsigned short* klg   = (unsigned short*)(wsf + 4163584);
    unsigned short* vgT   = (unsigned short*)(wsf + 4999168); // (B,C,NP) bf16
    float*          accum = wsf + 5834752;
    float*          ss    = wsf + 5834880;
    float*          yy    = qr;                             // reuse after flash
    float*          outp  = (float*)d_out;

    k_zero<<<1, 256, 0, stream>>>(accum);
    k_conv_rope<<<dim3(H_, B_, 3), 320, 0, stream>>>(x, wq, bq, wk, bk, wv, bv, fr,
                                                     qr, khg, klg, vgT);
    k_flash2<<<dim3(8, 204), 64, 0, stream>>>(qr, khg, klg, vgT, oo);
    k_bnstats<<<dim3(51, 8), 256, 0, stream>>>(x, oo, gamma, yy, accum);
    k_bnfin<<<1, 64, 0, stream>>>(accum, bnw, bnb, ss);
    k_bnapply<<<1024, 256, 0, stream>>>(yy, ss, outp);
}

// Round 7
// 485.870 us; speedup vs baseline: 3.9319x; 1.9340x over previous
//
#include <hip/hip_runtime.h>
#include <math.h>

#define B_ 8
#define C_ 64
#define H_ 50
#define W_ 65
#define N_ 3250
#define NP_ 3264            // padded positions (51*64)
#define SIDE_ 57.0f
#define EPS_ 1e-5f

typedef __attribute__((ext_vector_type(4))) float f32x4;
typedef __attribute__((ext_vector_type(8))) short s16x8;

__device__ __forceinline__ unsigned short rne_bf16(float f) {
    unsigned u = __builtin_bit_cast(unsigned, f);
    u += 0x7FFFu + ((u >> 16) & 1u);
    return (unsigned short)(u >> 16);
}
__device__ __forceinline__ float bf16_f(unsigned short h) {
    return __builtin_bit_cast(float, (unsigned)h << 16);
}

#define MFMA16(acc, a, b) \
    (acc) = __builtin_amdgcn_mfma_f32_16x16x32_bf16((a), (b), (acc), 0, 0, 0)

// ---------------- P1: weight prep -> wt[slot=cv*18+khkw*2+chunk][co][kk] split bf16 --
__global__ void k_wprep(const float* __restrict__ wq, const float* __restrict__ wk,
                        const float* __restrict__ wv,
                        unsigned short* __restrict__ wt_hi, unsigned short* __restrict__ wt_lo)
{
    const int idx  = blockIdx.x * 256 + threadIdx.x;    // 110592 total
    const int slot = idx >> 11;
    const int rem  = idx & 2047;
    const int co   = rem >> 5;
    const int kk   = rem & 31;
    const int cvv  = slot / 18;
    const int r2   = slot % 18;
    const int khkw = r2 >> 1;
    const int chunk= r2 & 1;
    const float* wp = (cvv == 0) ? wq : ((cvv == 1) ? wk : wv);
    const float v = wp[co * 576 + (chunk * 32 + kk) * 9 + khkw];
    const unsigned short hh = rne_bf16(v);
    wt_hi[idx] = hh;
    wt_lo[idx] = rne_bf16(v - bf16_f(hh));
}

// ---------------- P2: x prep -> xt[b][row 52][w' 68][ci 64] split bf16, zero halo ----
__global__ __launch_bounds__(256) void k_xprep(
    const float* __restrict__ x,
    unsigned short* __restrict__ xt_hi, unsigned short* __restrict__ xt_lo)
{
    const int row = blockIdx.x;        // 0..51 (= h+1)
    const int b   = blockIdx.y;
    const int t   = threadIdx.x;
    __shared__ float xls[64 * 66];
    const size_t ob = (size_t)(b * 52 + row) * 68 * 64;
    if (row == 0 || row == 51) {
        for (int s = t; s < 68 * 64; s += 256) { xt_hi[ob + s] = 0; xt_lo[ob + s] = 0; }
        return;
    }
    const int h = row - 1;
    for (int s = t; s < 64 * 65; s += 256) {
        const int ci = s / 65, w = s % 65;
        xls[ci * 66 + w] = x[((size_t)(b * 64 + ci) * 50 + h) * 65 + w];
    }
    __syncthreads();
    for (int s = t; s < 68 * 64; s += 256) {
        const int ci = s & 63, wq = s >> 6;
        const float v = (wq >= 1 && wq <= 65) ? xls[ci * 66 + (wq - 1)] : 0.f;
        const unsigned short hh = rne_bf16(v);
        xt_hi[ob + s] = hh;
        xt_lo[ob + s] = rne_bf16(v - bf16_f(hh));
    }
}

// ---------------- P3: RoPE trig table tt[pos-1][p] = (cos, sin) ---------------------
__global__ void k_trig(const float* __restrict__ fr, float* __restrict__ tt)
{
    const int idx = blockIdx.x * 256 + threadIdx.x;
    if (idx >= 3249 * 32) return;
    const int p = idx & 31;
    const float fi = (float)(idx >> 5);
    const float ty = floorf(fi / SIDE_);
    const float tx = fi - ty * SIDE_;
    float sn, cs;
    sincosf(tx * fr[p] + ty * fr[32 + p], &sn, &cs);
    tt[idx * 2]     = cs;
    tt[idx * 2 + 1] = sn;
}

// ---------------- K1: conv as 9 shifted GEMMs via split-bf16 MFMA -------------------
// grid (50, 8, 3cv), 256 thr (4 waves). wave = n-tile (16 co); 5 m-tiles {0,16,32,48,49}.
__global__ __launch_bounds__(256) void k_conv2(
    const unsigned short* __restrict__ xt_hi, const unsigned short* __restrict__ xt_lo,
    const unsigned short* __restrict__ wt_hi, const unsigned short* __restrict__ wt_lo,
    const float* __restrict__ bq, const float* __restrict__ bk, const float* __restrict__ bv,
    const float* __restrict__ tt,
    float* __restrict__ qr, unsigned short* __restrict__ khg,
    unsigned short* __restrict__ klg, unsigned short* __restrict__ vgT)
{
    const int h  = blockIdx.x;
    const int b  = blockIdx.y;
    const int cv = blockIdx.z;
    const int t  = threadIdx.x;
    const int l  = t & 63;
    const int nt = t >> 6;
    const int c  = l & 15;
    const int g  = l >> 4;

    __shared__ unsigned short vt[64 * 68];

    const float* bp = (cv == 0) ? bq : ((cv == 1) ? bk : bv);
    const int mstart[5] = {0, 16, 32, 48, 49};

    const f32x4 zero4 = {0.f, 0.f, 0.f, 0.f};
    f32x4 acc[5];
#pragma unroll
    for (int mt = 0; mt < 5; ++mt) acc[mt] = zero4;

#pragma unroll 1
    for (int chunk = 0; chunk < 2; ++chunk) {
#pragma unroll 1
        for (int khkw = 0; khkw < 9; ++khkw) {
            const int kh = khkw / 3, kw = khkw % 3;
            const int wb = ((cv * 18 + khkw * 2 + chunk) << 11) + (nt * 16 + c) * 32 + g * 8;
            const s16x8 bh = *(const s16x8*)(wt_hi + wb);
            const s16x8 bl = *(const s16x8*)(wt_lo + wb);
            const int ab0 = (((b * 52 + h + kh) * 68) + c + kw) * 64 + chunk * 32 + g * 8;
#pragma unroll
            for (int mt = 0; mt < 5; ++mt) {
                const int ai = ab0 + mstart[mt] * 64;
                const s16x8 ah = *(const s16x8*)(xt_hi + ai);
                const s16x8 al = *(const s16x8*)(xt_lo + ai);
                MFMA16(acc[mt], ah, bh);
                MFMA16(acc[mt], al, bh);
                MFMA16(acc[mt], ah, bl);
            }
        }
    }

    const int co = nt * 16 + c;
    const float bias = bp[co];

    if (cv == 2) {            // V: LDS transpose -> (B,C,NP) bf16, coalesced store
#pragma unroll
        for (int mt = 0; mt < 5; ++mt)
#pragma unroll
            for (int r = 0; r < 4; ++r) {
                const int mloc = mstart[mt] + g * 4 + r;
                vt[co * 68 + mloc] = rne_bf16(acc[mt][r] + bias);
            }
        __syncthreads();
        for (int s = t; s < 64 * 65; s += 256) {
            const int cc = s / 65, mm = s % 65;
            vgT[(size_t)(b * 64 + cc) * NP_ + h * 65 + mm] = vt[cc * 68 + mm];
        }
        return;
    }

    // q,k: bias + RoPE (pair partner via shfl_xor 1) + store
#pragma unroll
    for (int mt = 0; mt < 5; ++mt)
#pragma unroll
        for (int r = 0; r < 4; ++r) {
            const int mloc = mstart[mt] + g * 4 + r;
            const int pos  = h * 65 + mloc;
            float v = acc[mt][r] + bias;
            const float pr = __shfl_xor(v, 1);
            if (pos > 0) {
                const float2 cs2 = *(const float2*)(tt + ((size_t)(pos - 1) * 32 + (co >> 1)) * 2);
                v = (l & 1) ? (pr * cs2.y + v * cs2.x) : (v * cs2.x - pr * cs2.y);
            }
            if (cv == 0) {
                qr[(size_t)(b * N_ + pos) * 64 + co] = v;
            } else {
                const size_t idx = (size_t)(b * NP_ + pos) * 64 + co;
                const unsigned short hh = rne_bf16(v);
                khg[idx] = hh;
                klg[idx] = rne_bf16(v - bf16_f(hh));
            }
        }
}

// ---------------- K2: flash attention, 4 waves/block each owning a KV chunk ---------
// grid (8, 204), 256 thr. Wave wz covers tiles [wz*13, min(51,wz*13+13)); inner loop
// is the validated split-bf16 MFMA flash. LDS combine at the end (2 barriers).
__global__ __launch_bounds__(256) void k_flash4(
    const float* __restrict__ qr, const unsigned short* __restrict__ khg,
    const unsigned short* __restrict__ klg, const unsigned short* __restrict__ vgT,
    float* __restrict__ oo)
{
    const int b  = blockIdx.x;          // flat%8 == batch -> per-batch XCD pinning
    const int m0 = blockIdx.y << 4;
    const int t  = threadIdx.x;
    const int wz = t >> 6;              // wave id 0..3 (KV chunk)
    const int l  = t & 63;
    const int c  = l & 15;
    const int g  = l >> 4;

    __shared__ unsigned short pbh[4][1024];   // per-wave P-hi slice
    __shared__ unsigned short pbl[4][1024];
    __shared__ float obuf[4][1024];           // per-wave scaled O [row16][ch64]
    __shared__ float cm[4][16], cl[4][16];    // per-wave (m,l) per row

    unsigned short* pwh = &pbh[wz][0];
    unsigned short* pwl = &pbl[wz][0];

    // Q A-frags: row = lane&15 (m0+c), k = ks*32 + g*8 + j
    s16x8 qh[2], ql[2];
#pragma unroll
    for (int ks = 0; ks < 2; ++ks) {
        const float* qp = qr + ((size_t)(b * N_ + m0 + c) * 64 + ks * 32 + g * 8);
        const f32x4 f0 = *(const f32x4*)qp;
        const f32x4 f1 = *(const f32x4*)(qp + 4);
#pragma unroll
        for (int j = 0; j < 4; ++j) {
            const unsigned short h0 = rne_bf16(f0[j]);
            qh[ks][j]     = (short)h0;
            ql[ks][j]     = (short)rne_bf16(f0[j] - bf16_f(h0));
            const unsigned short h1 = rne_bf16(f1[j]);
            qh[ks][4 + j] = (short)h1;
            ql[ks][4 + j] = (short)rne_bf16(f1[j] - bf16_f(h1));
        }
    }

    const f32x4 zero4 = {0.f, 0.f, 0.f, 0.f};
    f32x4 osum[4];
#pragma unroll
    for (int ct = 0; ct < 4; ++ct) osum[ct] = zero4;
    float run_m[4], run_l[4];
#pragma unroll
    for (int r = 0; r < 4; ++r) { run_m[r] = -1e30f; run_l[r] = 0.f; }

    const int tile0 = wz * 13;
    const int tile1 = (wz == 3) ? 51 : tile0 + 13;
    for (int tile = tile0; tile < tile1; ++tile) {
        const int n0 = tile << 6;

        // ---- S = Q K^T (3-product split) ----
        f32x4 s4[4];
#pragma unroll
        for (int nt = 0; nt < 4; ++nt) s4[nt] = zero4;
#pragma unroll
        for (int ks = 0; ks < 2; ++ks) {
#pragma unroll
            for (int nt = 0; nt < 4; ++nt) {
                const size_t kb = (size_t)(b * NP_ + n0 + nt * 16 + c) * 64 + ks * 32 + g * 8;
                const s16x8 kh = *(const s16x8*)(khg + kb);
                const s16x8 kl = *(const s16x8*)(klg + kb);
                MFMA16(s4[nt], qh[ks], kh);
                MFMA16(s4[nt], ql[ks], kh);
                MFMA16(s4[nt], qh[ks], kl);
            }
        }

        if (tile == 50) {                  // mask padded columns (only wave 3)
#pragma unroll
            for (int nt = 0; nt < 4; ++nt)
                if (n0 + nt * 16 + c >= N_) {
                    const f32x4 m4 = {-1e30f, -1e30f, -1e30f, -1e30f};
                    s4[nt] = m4;
                }
        }

        // ---- online softmax: row r across the 16 c-lanes of group g ----
        float corr[4];
#pragma unroll
        for (int r = 0; r < 4; ++r) {
            float tm = fmaxf(fmaxf(s4[0][r], s4[1][r]), fmaxf(s4[2][r], s4[3][r]));
            tm = fmaxf(tm, __shfl_xor(tm, 1));
            tm = fmaxf(tm, __shfl_xor(tm, 2));
            tm = fmaxf(tm, __shfl_xor(tm, 4));
            tm = fmaxf(tm, __shfl_xor(tm, 8));
            const float mnew = fmaxf(run_m[r], tm);
            corr[r] = __expf(run_m[r] - mnew);
            float ts = 0.f;
#pragma unroll
            for (int nt = 0; nt < 4; ++nt) {
                const float p = __expf(s4[nt][r] - mnew);
                s4[nt][r] = p;
                ts += p;
            }
            ts += __shfl_xor(ts, 1);
            ts += __shfl_xor(ts, 2);
            ts += __shfl_xor(ts, 4);
            ts += __shfl_xor(ts, 8);
            run_l[r] = run_l[r] * corr[r] + ts;
            run_m[r] = mnew;
        }
#pragma unroll
        for (int ct = 0; ct < 4; ++ct)
#pragma unroll
            for (int r = 0; r < 4; ++r) osum[ct][r] *= corr[r];

        // ---- P split -> per-wave LDS slice (swizzled [m][n]) ----
#pragma unroll
        for (int nt = 0; nt < 4; ++nt)
#pragma unroll
            for (int r = 0; r < 4; ++r) {
                const int m   = g * 4 + r;
                const int off = m * 128 + ((((nt * 16 + c) * 2)) ^ ((m & 7) << 4));
                const float p = s4[nt][r];
                const unsigned short ph = rne_bf16(p);
                *(unsigned short*)((char*)pwh + off) = ph;
                *(unsigned short*)((char*)pwl + off) = rne_bf16(p - bf16_f(ph));
            }

        // ---- O += P V ----
#pragma unroll
        for (int ks = 0; ks < 2; ++ks) {
            const int aoff = c * 128 + (((ks * 64 + g * 16)) ^ ((c & 7) << 4));
            const s16x8 pah = *(const s16x8*)((const char*)pwh + aoff);
            const s16x8 pal = *(const s16x8*)((const char*)pwl + aoff);
#pragma unroll
            for (int ct = 0; ct < 4; ++ct) {
                const size_t vb = (size_t)(b * 64 + ct * 16 + c) * NP_ + n0 + ks * 32 + g * 8;
                const s16x8 vf = *(const s16x8*)(vgT + vb);
                MFMA16(osum[ct], pah, vf);
                MFMA16(osum[ct], pal, vf);
            }
        }
    }

    // ---- combine the 4 KV chunks (row-local math only) ----
    if (c == 0) {
#pragma unroll
        for (int r = 0; r < 4; ++r) {
            cm[wz][g * 4 + r] = run_m[r];
            cl[wz][g * 4 + r] = run_l[r];
        }
    }
    __syncthreads();
#pragma unroll
    for (int r = 0; r < 4; ++r) {
        const int row = g * 4 + r;
        const float M = fmaxf(fmaxf(cm[0][row], cm[1][row]), fmaxf(cm[2][row], cm[3][row]));
        const float w = __expf(run_m[r] - M);
#pragma unroll
        for (int ct = 0; ct < 4; ++ct)
            obuf[wz][row * 64 + ct * 16 + c] = osum[ct][r] * w;
    }
    __syncthreads();
    for (int i = t; i < 1024; i += 256) {
        const int row = i >> 6;
        const int m   = m0 + row;
        if (m >= N_) continue;
        const float M = fmaxf(fmaxf(cm[0][row], cm[1][row]), fmaxf(cm[2][row], cm[3][row]));
        float L = 0.f, o = 0.f;
#pragma unroll
        for (int z = 0; z < 4; ++z) {
            L += cl[z][row] * __expf(cm[z][row] - M);
            o += obuf[z][i];
        }
        oo[(size_t)(b * N_ + m) * 64 + (i & 63)] = o / L;
    }
}

// ---------------- K3: y = gamma*x + O^T, per-block partial sums (no atomics) --------
__global__ __launch_bounds__(256) void k_bnstats(
    const float* __restrict__ x, const float* __restrict__ oo,
    const float* __restrict__ gamma, float* __restrict__ yy, float* __restrict__ part)
{
    const int b    = blockIdx.y;
    const int m0   = blockIdx.x * 64;
    const int t    = threadIdx.x;
    const int lane = t & 63;
    const int blk  = blockIdx.y * 51 + blockIdx.x;
    __shared__ float ot[64 * 65];
    const float gm = gamma[0];
    {
        const int r4 = t >> 6;
#pragma unroll
        for (int i = 0; i < 16; ++i) {
            const int row = r4 + i * 4;
            const int m   = m0 + row;
            ot[row * 65 + lane] = (m < N_) ? oo[((size_t)b * N_ + m) * 64 + lane] : 0.f;
        }
    }
    __syncthreads();
    const int  m     = m0 + lane;
    const bool valid = (m < N_);
#pragma unroll
    for (int i = 0; i < 16; ++i) {
        const int c = (t >> 6) + (i << 2);
        float y = 0.f;
        if (valid) {
            const float xv = x[(size_t)(b * 64 + c) * N_ + m];
            y = gm * xv + ot[lane * 65 + c];
            yy[(size_t)(b * 64 + c) * N_ + m] = y;
        }
        float s1 = y, s2 = y * y;
#pragma unroll
        for (int d = 1; d < 64; d <<= 1) { s1 += __shfl_xor(s1, d); s2 += __shfl_xor(s2, d); }
        if (lane == 0) {
            part[(size_t)blk * 128 + c]      = s1;
            part[(size_t)blk * 128 + 64 + c] = s2;
        }
    }
}

// ---------------- K4: reduce partials, finalize scale/shift -------------------------
__global__ void k_bnfin(const float* __restrict__ part, const float* __restrict__ bnw,
                        const float* __restrict__ bnb, float* __restrict__ ss)
{
    const int c = threadIdx.x;              // 64
    float s1 = 0.f, s2 = 0.f;
    for (int k = 0; k < 408; ++k) {
        s1 += part[(size_t)k * 128 + c];
        s2 += part[(size_t)k * 128 + 64 + c];
    }
    const float cnt  = (float)(B_ * N_);
    const float mean = s1 / cnt;
    const float var  = s2 / cnt - mean * mean;
    const float sc   = bnw[c] * rsqrtf(var + EPS_);
    ss[c]      = sc;
    ss[64 + c] = bnb[c] - mean * sc;
}

// ---------------- K5: apply BN -------------------------------------------------------
__global__ __launch_bounds__(256) void k_bnapply(
    const float* __restrict__ yy, const float* __restrict__ ss, float* __restrict__ out)
{
    const int total = B_ * C_ * N_;
    for (int e = blockIdx.x * 256 + threadIdx.x; e < total; e += gridDim.x * 256) {
        const int c = (e / N_) & 63;
        out[e] = yy[e] * ss[c] + ss[64 + c];
    }
}

// ---------------- launch -------------------------------------------------------------
extern "C" void kernel_launch(void* const* d_in, const int* in_sizes, int n_in,
                              void* d_out, int out_size, void* d_ws, size_t ws_size,
                              hipStream_t stream) {
    const float* x     = (const float*)d_in[0];
    const float* wq    = (const float*)d_in[1];
    const float* bq    = (const float*)d_in[2];
    const float* wk    = (const float*)d_in[3];
    const float* bk    = (const float*)d_in[4];
    const float* wv    = (const float*)d_in[5];
    const float* bv    = (const float*)d_in[6];
    const float* fr    = (const float*)d_in[7];
    const float* gamma = (const float*)d_in[8];
    const float* bnw   = (const float*)d_in[9];
    const float* bnb   = (const float*)d_in[10];

    // ws layout (floats), total 6,352,064 f = 25.4 MB (<= proven 26.6 MB budget)
    float* wsf = (float*)d_ws;
    float*          qr    = wsf;                                  // 1,664,000
    unsigned short* khg   = (unsigned short*)(wsf + 1664000);     // 835,584 f each
    unsigned short* klg   = (unsigned short*)(wsf + 2499584);
    unsigned short* vgT   = (unsigned short*)(wsf + 3335168);
    float*          regB  = wsf + 4170752;                        // 2,128,960 f region
    unsigned short* xt_hi = (unsigned short*)regB;                // conv phase
    unsigned short* xt_lo = (unsigned short*)(regB + 905216);
    unsigned short* wt_hi = (unsigned short*)(regB + 1810432);
    unsigned short* wt_lo = (unsigned short*)(regB + 1865728);
    float*          tt    = regB + 1921024;                       // 207,936
    float*          oo    = regB;                                 // flash phase (1,664,000)
    float*          part  = wsf + 6299712;                        // 52,224
    float*          ss    = wsf + 6351936;                        // 128
    float*          yy    = qr;                                   // reuse after flash
    float*          outp  = (float*)d_out;

    k_wprep<<<432, 256, 0, stream>>>(wq, wk, wv, wt_hi, wt_lo);
    k_xprep<<<dim3(52, 8), 256, 0, stream>>>(x, xt_hi, xt_lo);
    k_trig<<<407, 256, 0, stream>>>(fr, tt);
    k_conv2<<<dim3(50, 8, 3), 256, 0, stream>>>(xt_hi, xt_lo, wt_hi, wt_lo,
                                                bq, bk, bv, tt, qr, khg, klg, vgT);
    k_flash4<<<dim3(8, 204), 256, 0, stream>>>(qr, khg, klg, vgT, oo);
    k_bnstats<<<dim3(51, 8), 256, 0, stream>>>(x, oo, gamma, yy, part);
    k_bnfin<<<1, 64, 0, stream>>>(part, bnw, bnb, ss);
    k_bnapply<<<1024, 256, 0, stream>>>(yy, ss, outp);
}

// Round 8
// 484.198 us; speedup vs baseline: 3.9455x; 1.0035x over previous
//
#include <hip/hip_runtime.h>
#include <math.h>

#define B_ 8
#define C_ 64
#define H_ 50
#define W_ 65
#define N_ 3250
#define NP_ 3264            // padded positions (51*64)
#define SIDE_ 57.0f
#define EPS_ 1e-5f

typedef __attribute__((ext_vector_type(4))) float f32x4;
typedef __attribute__((ext_vector_type(8))) short s16x8;

__device__ __forceinline__ unsigned short rne_bf16(float f) {
    unsigned u = __builtin_bit_cast(unsigned, f);
    u += 0x7FFFu + ((u >> 16) & 1u);
    return (unsigned short)(u >> 16);
}
__device__ __forceinline__ float bf16_f(unsigned short h) {
    return __builtin_bit_cast(float, (unsigned)h << 16);
}

#define MFMA16(acc, a, b) \
    (acc) = __builtin_amdgcn_mfma_f32_16x16x32_bf16((a), (b), (acc), 0, 0, 0)

// ---------------- P1: weight prep -> wt[slot=cv*18+khkw*2+chunk][co][kk] split bf16 --
__global__ void k_wprep(const float* __restrict__ wq, const float* __restrict__ wk,
                        const float* __restrict__ wv,
                        unsigned short* __restrict__ wt_hi, unsigned short* __restrict__ wt_lo)
{
    const int idx  = blockIdx.x * 256 + threadIdx.x;    // 110592 total
    const int slot = idx >> 11;
    const int rem  = idx & 2047;
    const int co   = rem >> 5;
    const int kk   = rem & 31;
    const int cvv  = slot / 18;
    const int r2   = slot % 18;
    const int khkw = r2 >> 1;
    const int chunk= r2 & 1;
    const float* wp = (cvv == 0) ? wq : ((cvv == 1) ? wk : wv);
    const float v = wp[co * 576 + (chunk * 32 + kk) * 9 + khkw];
    const unsigned short hh = rne_bf16(v);
    wt_hi[idx] = hh;
    wt_lo[idx] = rne_bf16(v - bf16_f(hh));
}

// ---------------- P2: x prep -> xt[b][row 52][w' 68][ci 64] split bf16, zero halo ----
__global__ __launch_bounds__(256) void k_xprep(
    const float* __restrict__ x,
    unsigned short* __restrict__ xt_hi, unsigned short* __restrict__ xt_lo)
{
    const int row = blockIdx.x;        // 0..51 (= h+1)
    const int b   = blockIdx.y;
    const int t   = threadIdx.x;
    __shared__ float xls[64 * 66];
    const size_t ob = (size_t)(b * 52 + row) * 68 * 64;
    if (row == 0 || row == 51) {
        for (int s = t; s < 68 * 64; s += 256) { xt_hi[ob + s] = 0; xt_lo[ob + s] = 0; }
        return;
    }
    const int h = row - 1;
    for (int s = t; s < 64 * 65; s += 256) {
        const int ci = s / 65, w = s % 65;
        xls[ci * 66 + w] = x[((size_t)(b * 64 + ci) * 50 + h) * 65 + w];
    }
    __syncthreads();
    for (int s = t; s < 68 * 64; s += 256) {
        const int ci = s & 63, wq = s >> 6;
        const float v = (wq >= 1 && wq <= 65) ? xls[ci * 66 + (wq - 1)] : 0.f;
        const unsigned short hh = rne_bf16(v);
        xt_hi[ob + s] = hh;
        xt_lo[ob + s] = rne_bf16(v - bf16_f(hh));
    }
}

// ---------------- P3: RoPE trig table tt[pos-1][p] = (cos, sin) ---------------------
__global__ void k_trig(const float* __restrict__ fr, float* __restrict__ tt)
{
    const int idx = blockIdx.x * 256 + threadIdx.x;
    if (idx >= 3249 * 32) return;
    const int p = idx & 31;
    const float fi = (float)(idx >> 5);
    const float ty = floorf(fi / SIDE_);
    const float tx = fi - ty * SIDE_;
    float sn, cs;
    sincosf(tx * fr[p] + ty * fr[32 + p], &sn, &cs);
    tt[idx * 2]     = cs;
    tt[idx * 2 + 1] = sn;
}

// ---------------- K1: conv as 9 shifted GEMMs via split-bf16 MFMA -------------------
// grid (50, 8, 3cv), 256 thr (4 waves). wave = n-tile (16 co); 5 m-tiles {0,16,32,48,49}.
__global__ __launch_bounds__(256) void k_conv2(
    const unsigned short* __restrict__ xt_hi, const unsigned short* __restrict__ xt_lo,
    const unsigned short* __restrict__ wt_hi, const unsigned short* __restrict__ wt_lo,
    const float* __restrict__ bq, const float* __restrict__ bk, const float* __restrict__ bv,
    const float* __restrict__ tt,
    float* __restrict__ qr, unsigned short* __restrict__ khg,
    unsigned short* __restrict__ klg, unsigned short* __restrict__ vgT)
{
    const int h  = blockIdx.x;
    const int b  = blockIdx.y;
    const int cv = blockIdx.z;
    const int t  = threadIdx.x;
    const int l  = t & 63;
    const int nt = t >> 6;
    const int c  = l & 15;
    const int g  = l >> 4;

    __shared__ unsigned short vt[64 * 68];

    const float* bp = (cv == 0) ? bq : ((cv == 1) ? bk : bv);
    const int mstart[5] = {0, 16, 32, 48, 49};

    const f32x4 zero4 = {0.f, 0.f, 0.f, 0.f};
    f32x4 acc[5];
#pragma unroll
    for (int mt = 0; mt < 5; ++mt) acc[mt] = zero4;

#pragma unroll 1
    for (int chunk = 0; chunk < 2; ++chunk) {
#pragma unroll 1
        for (int khkw = 0; khkw < 9; ++khkw) {
            const int kh = khkw / 3, kw = khkw % 3;
            const int wb = ((cv * 18 + khkw * 2 + chunk) << 11) + (nt * 16 + c) * 32 + g * 8;
            const s16x8 bh = *(const s16x8*)(wt_hi + wb);
            const s16x8 bl = *(const s16x8*)(wt_lo + wb);
            const int ab0 = (((b * 52 + h + kh) * 68) + c + kw) * 64 + chunk * 32 + g * 8;
#pragma unroll
            for (int mt = 0; mt < 5; ++mt) {
                const int ai = ab0 + mstart[mt] * 64;
                const s16x8 ah = *(const s16x8*)(xt_hi + ai);
                const s16x8 al = *(const s16x8*)(xt_lo + ai);
                MFMA16(acc[mt], ah, bh);
                MFMA16(acc[mt], al, bh);
                MFMA16(acc[mt], ah, bl);
            }
        }
    }

    const int co = nt * 16 + c;
    const float bias = bp[co];

    if (cv == 2) {            // V: LDS transpose -> (B,C,NP) bf16, coalesced store
#pragma unroll
        for (int mt = 0; mt < 5; ++mt)
#pragma unroll
            for (int r = 0; r < 4; ++r) {
                const int mloc = mstart[mt] + g * 4 + r;
                vt[co * 68 + mloc] = rne_bf16(acc[mt][r] + bias);
            }
        __syncthreads();
        for (int s = t; s < 64 * 65; s += 256) {
            const int cc = s / 65, mm = s % 65;
            vgT[(size_t)(b * 64 + cc) * NP_ + h * 65 + mm] = vt[cc * 68 + mm];
        }
        return;
    }

    // q,k: bias + RoPE (pair partner via shfl_xor 1) + store
#pragma unroll
    for (int mt = 0; mt < 5; ++mt)
#pragma unroll
        for (int r = 0; r < 4; ++r) {
            const int mloc = mstart[mt] + g * 4 + r;
            const int pos  = h * 65 + mloc;
            float v = acc[mt][r] + bias;
            const float pr = __shfl_xor(v, 1);
            if (pos > 0) {
                const float2 cs2 = *(const float2*)(tt + ((size_t)(pos - 1) * 32 + (co >> 1)) * 2);
                v = (l & 1) ? (pr * cs2.y + v * cs2.x) : (v * cs2.x - pr * cs2.y);
            }
            if (cv == 0) {
                qr[(size_t)(b * N_ + pos) * 64 + co] = v;
            } else {
                const size_t idx = (size_t)(b * NP_ + pos) * 64 + co;
                const unsigned short hh = rne_bf16(v);
                khg[idx] = hh;
                klg[idx] = rne_bf16(v - bf16_f(hh));
            }
        }
}

// ---------------- K2: flash attention, 4 waves/block each owning a KV chunk ---------
// grid (8, 204), 256 thr. Wave wz covers tiles [wz*13, min(51,wz*13+13)).
// LDS: P-buffers (16KB) UNION obuf (16KB) -- obuf only written after the barrier that
// guarantees all P reads are done. 16.9KB/block -> ~6 blocks/CU (VGPR-capped).
__global__ __launch_bounds__(256) void k_flash4(
    const float* __restrict__ qr, const unsigned short* __restrict__ khg,
    const unsigned short* __restrict__ klg, const unsigned short* __restrict__ vgT,
    float* __restrict__ oo)
{
    const int b  = blockIdx.x;          // flat%8 == batch -> per-batch XCD pinning
    const int m0 = blockIdx.y << 4;
    const int t  = threadIdx.x;
    const int wz = t >> 6;              // wave id 0..3 (KV chunk)
    const int l  = t & 63;
    const int c  = l & 15;
    const int g  = l >> 4;

    __shared__ char smem[16384];              // pbh[4][1024]us + pbl[4][1024]us | obuf[4][1024]f
    __shared__ float cm[4][16], cl[4][16];    // per-wave (m,l) per row

    unsigned short* pwh = (unsigned short*)(smem + wz * 2048);
    unsigned short* pwl = (unsigned short*)(smem + 8192 + wz * 2048);
    float* obuf = (float*)smem;               // [4][1024], valid after combine barrier

    // Q A-frags: row = lane&15 (m0+c), k = ks*32 + g*8 + j
    s16x8 qh[2], ql[2];
#pragma unroll
    for (int ks = 0; ks < 2; ++ks) {
        const float* qp = qr + ((size_t)(b * N_ + m0 + c) * 64 + ks * 32 + g * 8);
        const f32x4 f0 = *(const f32x4*)qp;
        const f32x4 f1 = *(const f32x4*)(qp + 4);
#pragma unroll
        for (int j = 0; j < 4; ++j) {
            const unsigned short h0 = rne_bf16(f0[j]);
            qh[ks][j]     = (short)h0;
            ql[ks][j]     = (short)rne_bf16(f0[j] - bf16_f(h0));
            const unsigned short h1 = rne_bf16(f1[j]);
            qh[ks][4 + j] = (short)h1;
            ql[ks][4 + j] = (short)rne_bf16(f1[j] - bf16_f(h1));
        }
    }

    const f32x4 zero4 = {0.f, 0.f, 0.f, 0.f};
    f32x4 osum[4];
#pragma unroll
    for (int ct = 0; ct < 4; ++ct) osum[ct] = zero4;
    float run_m[4], run_l[4];
#pragma unroll
    for (int r = 0; r < 4; ++r) { run_m[r] = -1e30f; run_l[r] = 0.f; }

    const int tile0 = wz * 13;
    const int tile1 = (wz == 3) ? 51 : tile0 + 13;
    for (int tile = tile0; tile < tile1; ++tile) {
        const int n0 = tile << 6;

        // ---- S = Q K^T (3-product split) ----
        f32x4 s4[4];
#pragma unroll
        for (int nt = 0; nt < 4; ++nt) s4[nt] = zero4;
#pragma unroll
        for (int ks = 0; ks < 2; ++ks) {
#pragma unroll
            for (int nt = 0; nt < 4; ++nt) {
                const size_t kb = (size_t)(b * NP_ + n0 + nt * 16 + c) * 64 + ks * 32 + g * 8;
                const s16x8 kh = *(const s16x8*)(khg + kb);
                const s16x8 kl = *(const s16x8*)(klg + kb);
                MFMA16(s4[nt], qh[ks], kh);
                MFMA16(s4[nt], ql[ks], kh);
                MFMA16(s4[nt], qh[ks], kl);
            }
        }

        if (tile == 50) {                  // mask padded columns (only wave 3)
#pragma unroll
            for (int nt = 0; nt < 4; ++nt)
                if (n0 + nt * 16 + c >= N_) {
                    const f32x4 m4 = {-1e30f, -1e30f, -1e30f, -1e30f};
                    s4[nt] = m4;
                }
        }

        // ---- online softmax: row r across the 16 c-lanes of group g ----
        float corr[4];
#pragma unroll
        for (int r = 0; r < 4; ++r) {
            float tm = fmaxf(fmaxf(s4[0][r], s4[1][r]), fmaxf(s4[2][r], s4[3][r]));
            tm = fmaxf(tm, __shfl_xor(tm, 1));
            tm = fmaxf(tm, __shfl_xor(tm, 2));
            tm = fmaxf(tm, __shfl_xor(tm, 4));
            tm = fmaxf(tm, __shfl_xor(tm, 8));
            const float mnew = fmaxf(run_m[r], tm);
            corr[r] = __expf(run_m[r] - mnew);
            float ts = 0.f;
#pragma unroll
            for (int nt = 0; nt < 4; ++nt) {
                const float p = __expf(s4[nt][r] - mnew);
                s4[nt][r] = p;
                ts += p;
            }
            ts += __shfl_xor(ts, 1);
            ts += __shfl_xor(ts, 2);
            ts += __shfl_xor(ts, 4);
            ts += __shfl_xor(ts, 8);
            run_l[r] = run_l[r] * corr[r] + ts;
            run_m[r] = mnew;
        }
#pragma unroll
        for (int ct = 0; ct < 4; ++ct)
#pragma unroll
            for (int r = 0; r < 4; ++r) osum[ct][r] *= corr[r];

        // ---- P split -> per-wave LDS slice (swizzled [m][n]) ----
#pragma unroll
        for (int nt = 0; nt < 4; ++nt)
#pragma unroll
            for (int r = 0; r < 4; ++r) {
                const int m   = g * 4 + r;
                const int off = m * 128 + ((((nt * 16 + c) * 2)) ^ ((m & 7) << 4));
                const float p = s4[nt][r];
                const unsigned short ph = rne_bf16(p);
                *(unsigned short*)((char*)pwh + off) = ph;
                *(unsigned short*)((char*)pwl + off) = rne_bf16(p - bf16_f(ph));
            }

        // ---- O += P V ----
#pragma unroll
        for (int ks = 0; ks < 2; ++ks) {
            const int aoff = c * 128 + (((ks * 64 + g * 16)) ^ ((c & 7) << 4));
            const s16x8 pah = *(const s16x8*)((const char*)pwh + aoff);
            const s16x8 pal = *(const s16x8*)((const char*)pwl + aoff);
#pragma unroll
            for (int ct = 0; ct < 4; ++ct) {
                const size_t vb = (size_t)(b * 64 + ct * 16 + c) * NP_ + n0 + ks * 32 + g * 8;
                const s16x8 vf = *(const s16x8*)(vgT + vb);
                MFMA16(osum[ct], pah, vf);
                MFMA16(osum[ct], pal, vf);
            }
        }
    }

    // ---- combine the 4 KV chunks (row-local math only) ----
    if (c == 0) {
#pragma unroll
        for (int r = 0; r < 4; ++r) {
            cm[wz][g * 4 + r] = run_m[r];
            cl[wz][g * 4 + r] = run_l[r];
        }
    }
    __syncthreads();   // all P reads done + cm/cl visible -> safe to reuse smem as obuf
#pragma unroll
    for (int r = 0; r < 4; ++r) {
        const int row = g * 4 + r;
        const float M = fmaxf(fmaxf(cm[0][row], cm[1][row]), fmaxf(cm[2][row], cm[3][row]));
        const float w = __expf(run_m[r] - M);
#pragma unroll
        for (int ct = 0; ct < 4; ++ct)
            obuf[wz * 1024 + row * 64 + ct * 16 + c] = osum[ct][r] * w;
    }
    __syncthreads();
    for (int i = t; i < 1024; i += 256) {
        const int row = i >> 6;
        const int m   = m0 + row;
        if (m >= N_) continue;
        const float M = fmaxf(fmaxf(cm[0][row], cm[1][row]), fmaxf(cm[2][row], cm[3][row]));
        float L = 0.f, o = 0.f;
#pragma unroll
        for (int z = 0; z < 4; ++z) {
            L += cl[z][row] * __expf(cm[z][row] - M);
            o += obuf[z * 1024 + i];
        }
        oo[(size_t)(b * N_ + m) * 64 + (i & 63)] = o / L;
    }
}

// ---------------- K3: y = gamma*x + O^T, per-block partial sums (no atomics) --------
__global__ __launch_bounds__(256) void k_bnstats(
    const float* __restrict__ x, const float* __restrict__ oo,
    const float* __restrict__ gamma, float* __restrict__ yy, float* __restrict__ part)
{
    const int b    = blockIdx.y;
    const int m0   = blockIdx.x * 64;
    const int t    = threadIdx.x;
    const int lane = t & 63;
    const int blk  = blockIdx.y * 51 + blockIdx.x;
    __shared__ float ot[64 * 65];
    const float gm = gamma[0];
    {
        const int r4 = t >> 6;
#pragma unroll
        for (int i = 0; i < 16; ++i) {
            const int row = r4 + i * 4;
            const int m   = m0 + row;
            ot[row * 65 + lane] = (m < N_) ? oo[((size_t)b * N_ + m) * 64 + lane] : 0.f;
        }
    }
    __syncthreads();
    const int  m     = m0 + lane;
    const bool valid = (m < N_);
#pragma unroll
    for (int i = 0; i < 16; ++i) {
        const int c = (t >> 6) + (i << 2);
        float y = 0.f;
        if (valid) {
            const float xv = x[(size_t)(b * 64 + c) * N_ + m];
            y = gm * xv + ot[lane * 65 + c];
            yy[(size_t)(b * 64 + c) * N_ + m] = y;
        }
        float s1 = y, s2 = y * y;
#pragma unroll
        for (int d = 1; d < 64; d <<= 1) { s1 += __shfl_xor(s1, d); s2 += __shfl_xor(s2, d); }
        if (lane == 0) {
            part[(size_t)blk * 128 + c]      = s1;
            part[(size_t)blk * 128 + 64 + c] = s2;
        }
    }
}

// ---------------- K4: reduce partials, finalize scale/shift -------------------------
__global__ void k_bnfin(const float* __restrict__ part, const float* __restrict__ bnw,
                        const float* __restrict__ bnb, float* __restrict__ ss)
{
    const int c = threadIdx.x;              // 64
    float s1 = 0.f, s2 = 0.f;
    for (int k = 0; k < 408; ++k) {
        s1 += part[(size_t)k * 128 + c];
        s2 += part[(size_t)k * 128 + 64 + c];
    }
    const float cnt  = (float)(B_ * N_);
    const float mean = s1 / cnt;
    const float var  = s2 / cnt - mean * mean;
    const float sc   = bnw[c] * rsqrtf(var + EPS_);
    ss[c]      = sc;
    ss[64 + c] = bnb[c] - mean * sc;
}

// ---------------- K5: apply BN -------------------------------------------------------
__global__ __launch_bounds__(256) void k_bnapply(
    const float* __restrict__ yy, const float* __restrict__ ss, float* __restrict__ out)
{
    const int total = B_ * C_ * N_;
    for (int e = blockIdx.x * 256 + threadIdx.x; e < total; e += gridDim.x * 256) {
        const int c = (e / N_) & 63;
        out[e] = yy[e] * ss[c] + ss[64 + c];
    }
}

// ---------------- launch -------------------------------------------------------------
extern "C" void kernel_launch(void* const* d_in, const int* in_sizes, int n_in,
                              void* d_out, int out_size, void* d_ws, size_t ws_size,
                              hipStream_t stream) {
    const float* x     = (const float*)d_in[0];
    const float* wq    = (const float*)d_in[1];
    const float* bq    = (const float*)d_in[2];
    const float* wk    = (const float*)d_in[3];
    const float* bk    = (const float*)d_in[4];
    const float* wv    = (const float*)d_in[5];
    const float* bv    = (const float*)d_in[6];
    const float* fr    = (const float*)d_in[7];
    const float* gamma = (const float*)d_in[8];
    const float* bnw   = (const float*)d_in[9];
    const float* bnb   = (const float*)d_in[10];

    // ws layout (floats), total 6,352,064 f = 25.4 MB (<= proven 26.6 MB budget)
    float* wsf = (float*)d_ws;
    float*          qr    = wsf;                                  // 1,664,000
    unsigned short* khg   = (unsigned short*)(wsf + 1664000);     // 835,584 f each
    unsigned short* klg   = (unsigned short*)(wsf + 2499584);
    unsigned short* vgT   = (unsigned short*)(wsf + 3335168);
    float*          regB  = wsf + 4170752;                        // 2,128,960 f region
    unsigned short* xt_hi = (unsigned short*)regB;                // conv phase
    unsigned short* xt_lo = (unsigned short*)(regB + 905216);
    unsigned short* wt_hi = (unsigned short*)(regB + 1810432);
    unsigned short* wt_lo = (unsigned short*)(regB + 1865728);
    float*          tt    = regB + 1921024;                       // 207,936
    float*          oo    = regB;                                 // flash phase (1,664,000)
    float*          part  = wsf + 6299712;                        // 52,224
    float*          ss    = wsf + 6351936;                        // 128
    float*          yy    = qr;                                   // reuse after flash
    float*          outp  = (float*)d_out;

    k_wprep<<<432, 256, 0, stream>>>(wq, wk, wv, wt_hi, wt_lo);
    k_xprep<<<dim3(52, 8), 256, 0, stream>>>(x, xt_hi, xt_lo);
    k_trig<<<407, 256, 0, stream>>>(fr, tt);
    k_conv2<<<dim3(50, 8, 3), 256, 0, stream>>>(xt_hi, xt_lo, wt_hi, wt_lo,
                                                bq, bk, bv, tt, qr, khg, klg, vgT);
    k_flash4<<<dim3(8, 204), 256, 0, stream>>>(qr, khg, klg, vgT, oo);
    k_bnstats<<<dim3(51, 8), 256, 0, stream>>>(x, oo, gamma, yy, part);
    k_bnfin<<<1, 64, 0, stream>>>(part, bnw, bnb, ss);
    k_bnapply<<<1024, 256, 0, stream>>>(yy, ss, outp);
}